// Round 11
// baseline (145.793 us; speedup 1.0000x reference)
//
#include <hip/hip_runtime.h>

// Flash attention forward, fp32 in/out, fp16 MFMA compute.
// B=8, SQ=SK=4096, D=64. scores = (Q/x5) K^T ; softmax ; O = P V.
// R11 = R10 with LDS cut to EXACTLY 40 KB -> 4 blocks/CU (16 waves, was 3/8):
//  - sP: one 8 KB buffer per wave shared across both M-tiles (mt0 full
//    softmax->write->read->PV, then mt1 reuses it; DS ops are in-order per
//    wave so overwrite-after-read is safe), unpadded, XOR-8 key-block swizzle
//    (b64 writes / b128 reads both <=2-way = free).
//  - sK 16K + sV 16K + sP 8K = 40960 B; __launch_bounds__(256,4).
// Rest identical to R10: global_load_lds dbuf staging, 1 barrier/iter,
// XCD-affine flat grid, exp2-domain softmax, KSPLIT=4, fp16 partials.

typedef _Float16 f16x8 __attribute__((ext_vector_type(8)));
typedef _Float16 f16x4 __attribute__((ext_vector_type(4)));
typedef __fp16   h16x2 __attribute__((ext_vector_type(2)));
typedef float    f32x4 __attribute__((ext_vector_type(4)));

constexpr int kB  = 8;
constexpr int kSQ = 4096;
constexpr int kSK = 4096;
constexpr int kD  = 64;
constexpr int KSPLIT = 4;
constexpr int SKH = kSK / KSPLIT;     // 1024 keys per split
constexpr int BQ  = 128;              // 4 waves x 32 Q rows
constexpr int BK  = 64;
constexpr size_t APART = (size_t)kB * kSQ * kD;
constexpr float kLog2e = 1.44269504088896340736f;

static __device__ __forceinline__ f16x4 pack4(float a, float b, float c, float d) {
    h16x2 p0 = __builtin_amdgcn_cvt_pkrtz(a, b);
    h16x2 p1 = __builtin_amdgcn_cvt_pkrtz(c, d);
    f16x4 r;
    r[0] = (_Float16)p0[0]; r[1] = (_Float16)p0[1];
    r[2] = (_Float16)p1[0]; r[3] = (_Float16)p1[1];
    return r;
}
static __device__ __forceinline__ f16x8 pack8(const float4& a, const float4& c) {
    f16x4 lo = pack4(a.x, a.y, a.z, a.w);
    f16x4 hi = pack4(c.x, c.y, c.z, c.w);
    f16x8 f;
    f[0] = lo[0]; f[1] = lo[1]; f[2] = lo[2]; f[3] = lo[3];
    f[4] = hi[0]; f[5] = hi[1]; f[6] = hi[2]; f[7] = hi[3];
    return f;
}

typedef const __attribute__((address_space(1))) unsigned int* gu32p;
typedef __attribute__((address_space(3))) unsigned int* lu32p;
static __device__ __forceinline__ void gload_lds16(const void* g, void* l) {
    __builtin_amdgcn_global_load_lds((gu32p)g, (lu32p)l, 16, 0, 0);
}

// ---------------- pre-pass: K -> Kh (swizzled fp16), V -> Vt (transposed,
// tiled, swizzled fp16). Kh[b][k][blk fb^(k&7)][8]; Vt[b][kt][f][blk kb^(f&7)][8].
__global__ __launch_bounds__(256, 2)
void fattn_prepass(const float* __restrict__ Kg,
                   const float* __restrict__ Vg,
                   _Float16* __restrict__ Kh,
                   _Float16* __restrict__ Vt)
{
    __shared__ _Float16 tr[kD][BK];

    const int tid = threadIdx.x;
    const int kt  = blockIdx.x;
    const int b   = blockIdx.y;

    const int k = tid >> 2;
    const int p = tid & 3;
    const int gk = kt * BK + k;

    {
        const float* src = Kg + ((size_t)b * kSK + gk) * kD + p * 16;
        const float4 a0 = *(const float4*)(src + 0);
        const float4 a1 = *(const float4*)(src + 4);
        const float4 a2 = *(const float4*)(src + 8);
        const float4 a3 = *(const float4*)(src + 12);
        _Float16* dst = Kh + ((size_t)b * kSK + gk) * kD;
        const int fb0 = 2 * p, fb1 = 2 * p + 1;
        *(f16x8*)&dst[(fb0 ^ (gk & 7)) * 8] = pack8(a0, a1);
        *(f16x8*)&dst[(fb1 ^ (gk & 7)) * 8] = pack8(a2, a3);
    }
    {
        const float* src = Vg + ((size_t)b * kSK + gk) * kD + p * 16;
        const float4 a0 = *(const float4*)(src + 0);
        const float4 a1 = *(const float4*)(src + 4);
        const float4 a2 = *(const float4*)(src + 8);
        const float4 a3 = *(const float4*)(src + 12);
        const float v[16] = {a0.x,a0.y,a0.z,a0.w, a1.x,a1.y,a1.z,a1.w,
                             a2.x,a2.y,a2.z,a2.w, a3.x,a3.y,a3.z,a3.w};
#pragma unroll
        for (int j = 0; j < 16; ++j)
            tr[p * 16 + j][k] = (_Float16)v[j];
    }
    __syncthreads();
    {
        const int f  = tid >> 2;
        const int p2 = tid & 3;
        const f16x8 b0 = *(const f16x8*)&tr[f][p2 * 16 + 0];
        const f16x8 b1 = *(const f16x8*)&tr[f][p2 * 16 + 8];
        _Float16* dst = Vt + (((size_t)b * 64 + kt) * kD + f) * BK;
        const int kb0 = 2 * p2, kb1 = 2 * p2 + 1;
        *(f16x8*)&dst[(kb0 ^ (f & 7)) * 8] = b0;
        *(f16x8*)&dst[(kb1 ^ (f & 7)) * 8] = b1;
    }
}

// ---------------- main partial kernel ----------------
__global__ __launch_bounds__(256, 4)
void fattn_partial(const float* __restrict__ Qg,
                   const _Float16* __restrict__ Kh,
                   const _Float16* __restrict__ Vt,
                   const float* __restrict__ sdiv,
                   _Float16* __restrict__ Ap,   // [KSPLIT][B][SQ][D] unnormalized
                   float2* __restrict__ MLp)    // [KSPLIT][B][SQ] (m,l) exp2-domain
{
    __shared__ __align__(16) _Float16 sK[2][BK * kD];   // 16 KB
    __shared__ __align__(16) _Float16 sV[2][kD * BK];   // 16 KB
    __shared__ __align__(16) _Float16 sP[4][16][BK];    // 8 KB, shared across mt

    const int tid  = threadIdx.x;
    const int w    = tid >> 6;
    const int lane = tid & 63;
    const int l16  = lane & 15;
    const int quad = lane >> 4;
    const int sw   = (quad ^ (l16 & 7)) * 8;   // K/V fragment swizzle
    const int swp  = (l16 & 7) * 8;            // sP key-block swizzle

    // XCD-affine decode: flat = c + 32*q; c = (b,ks); all 32 q-blocks of one
    // K/V stream share an XCD (flat%8 invariant across q).
    const int flat = blockIdx.x;
    const int c    = flat & 31;
    const int qi   = flat >> 5;
    const int b    = c >> 2;      // KSPLIT = 4
    const int ks   = c & 3;
    const int qb   = qi * BQ;

    const float qscale = kLog2e / sdiv[0];   // exp2 domain

    const float* Qb = Qg + ((size_t)b * kSQ + qb) * kD;
    const _Float16* Khb = Kh + ((size_t)b * kSK + (size_t)ks * SKH) * kD;
    const _Float16* Vtb = Vt + (((size_t)b * 64 + (size_t)ks * (SKH / BK)) * kD) * BK;

    // ---- Q fragments: 2 M-tiles per wave, pre-scaled ----
    f16x8 qf[2][2];
#pragma unroll
    for (int mt = 0; mt < 2; ++mt) {
        const float* qrow = Qb + (size_t)(w * 32 + mt * 16 + l16) * kD;
#pragma unroll
        for (int kk = 0; kk < 2; ++kk) {
            const float4 a = *(const float4*)(qrow + kk * 32 + quad * 8);
            const float4 cc = *(const float4*)(qrow + kk * 32 + quad * 8 + 4);
            float4 as = make_float4(a.x * qscale, a.y * qscale, a.z * qscale, a.w * qscale);
            float4 cs = make_float4(cc.x * qscale, cc.y * qscale, cc.z * qscale, cc.w * qscale);
            qf[mt][kk] = pack8(as, cs);
        }
    }

    // ---- async staging: 4 global_load_lds per wave ----
    auto stage = [&](int kt, int buf) {
        const char* gk = (const char*)(Khb + (size_t)kt * BK * kD) + w * 2048 + lane * 16;
        const char* gv = (const char*)(Vtb + (size_t)kt * kD * BK) + w * 2048 + lane * 16;
        char* lk = (char*)&sK[buf][0] + w * 2048;
        char* lv = (char*)&sV[buf][0] + w * 2048;
        gload_lds16(gk,        lk);
        gload_lds16(gk + 1024, lk + 1024);
        gload_lds16(gv,        lv);
        gload_lds16(gv + 1024, lv + 1024);
    };

    f32x4 o[2][4];
    float m_i[2] = {-1e30f, -1e30f}, l_i[2] = {0.0f, 0.0f};
#pragma unroll
    for (int mt = 0; mt < 2; ++mt)
#pragma unroll
        for (int dt = 0; dt < 4; ++dt)
#pragma unroll
            for (int r = 0; r < 4; ++r) o[mt][dt][r] = 0.0f;

    stage(0, 0);
    __syncthreads();

    const int nIter = SKH / BK;   // 16
    for (int kt = 0; kt < nIter; ++kt) {
        const int buf = kt & 1;
        const bool more = (kt + 1 < nIter);
        if (more) stage(kt + 1, buf ^ 1);   // DMA in flight during compute

        // ---- S^T = K Q^T ----
        f32x4 s[2][4];
#pragma unroll
        for (int nt = 0; nt < 4; ++nt) {
            const int krow = (nt * 16 + l16) * kD;
            const f16x8 kf0 = *(const f16x8*)&sK[buf][krow + sw];
            const f16x8 kf1 = *(const f16x8*)&sK[buf][krow + (sw ^ 32)];
#pragma unroll
            for (int mt = 0; mt < 2; ++mt) {
                f32x4 acc;
#pragma unroll
                for (int r = 0; r < 4; ++r) acc[r] = 0.0f;
                acc = __builtin_amdgcn_mfma_f32_16x16x32_f16(kf0, qf[mt][0], acc, 0, 0, 0);
                acc = __builtin_amdgcn_mfma_f32_16x16x32_f16(kf1, qf[mt][1], acc, 0, 0, 0);
                s[mt][nt] = acc;
            }
        }

        // ---- vf reads hoisted: softmax below covers their latency ----
        f16x8 vf[4][2];
#pragma unroll
        for (int dt = 0; dt < 4; ++dt) {
            const int frow = (dt * 16 + l16) * BK;
            vf[dt][0] = *(const f16x8*)&sV[buf][frow + sw];
            vf[dt][1] = *(const f16x8*)&sV[buf][frow + (sw ^ 32)];
        }

        // ---- per-M-tile: softmax -> sP write -> pf read -> PV.
        //      One shared 8 KB sP buffer; DS ops are in-order per wave, so
        //      mt=1's writes can't pass mt=0's pf reads. ----
#pragma unroll
        for (int mt = 0; mt < 2; ++mt) {
            float ra = fmaxf(fmaxf(s[mt][0][0], s[mt][0][1]), fmaxf(s[mt][0][2], s[mt][0][3]));
            float rb = fmaxf(fmaxf(s[mt][1][0], s[mt][1][1]), fmaxf(s[mt][1][2], s[mt][1][3]));
            float rc = fmaxf(fmaxf(s[mt][2][0], s[mt][2][1]), fmaxf(s[mt][2][2], s[mt][2][3]));
            float rd = fmaxf(fmaxf(s[mt][3][0], s[mt][3][1]), fmaxf(s[mt][3][2], s[mt][3][3]));
            float rm = fmaxf(fmaxf(ra, rb), fmaxf(rc, rd));
            rm = fmaxf(rm, __shfl_xor(rm, 16, 64));
            rm = fmaxf(rm, __shfl_xor(rm, 32, 64));
            const float mnew = fmaxf(m_i[mt], rm);
            float rs = 0.0f;
#pragma unroll
            for (int nt = 0; nt < 4; ++nt)
#pragma unroll
                for (int r = 0; r < 4; ++r) {
                    const float p = __builtin_amdgcn_exp2f(s[mt][nt][r] - mnew);
                    s[mt][nt][r] = p;
                    rs += p;
                }
            rs += __shfl_xor(rs, 16, 64);
            rs += __shfl_xor(rs, 32, 64);
            if (!__all(mnew == m_i[mt])) {      // max moved: rescale
                const float alpha = __builtin_amdgcn_exp2f(m_i[mt] - mnew);
                l_i[mt] *= alpha;
#pragma unroll
                for (int dt = 0; dt < 4; ++dt)
#pragma unroll
                    for (int r = 0; r < 4; ++r) o[mt][dt][r] *= alpha;
            }
            m_i[mt] = mnew;
            l_i[mt] += rs;

            // P -> sP (swizzled, unpadded; b64 writes <=2-way)
#pragma unroll
            for (int nt = 0; nt < 4; ++nt)
                *(f16x4*)&sP[w][l16][(nt * 16 + quad * 4) ^ swp] =
                    pack4(s[mt][nt][0], s[mt][nt][1], s[mt][nt][2], s[mt][nt][3]);

            // pf reads (b128 <=2-way) + PV
            const f16x8 pf0 = *(const f16x8*)&sP[w][l16][(quad * 8) ^ swp];
            const f16x8 pf1 = *(const f16x8*)&sP[w][l16][(32 + quad * 8) ^ swp];
#pragma unroll
            for (int dt = 0; dt < 4; ++dt) {
                o[mt][dt] = __builtin_amdgcn_mfma_f32_16x16x32_f16(vf[dt][0], pf0, o[mt][dt], 0, 0, 0);
                o[mt][dt] = __builtin_amdgcn_mfma_f32_16x16x32_f16(vf[dt][1], pf1, o[mt][dt], 0, 0, 0);
            }
        }

        __syncthreads();   // drains prefetch DMA (vmcnt) + LDS
    }

    // ---- epilogue ----
    _Float16* Ab = Ap + (size_t)ks * APART + ((size_t)b * kSQ + qb) * kD;
    float2* MLb = MLp + (size_t)ks * kB * kSQ + (size_t)b * kSQ + qb;
#pragma unroll
    for (int mt = 0; mt < 2; ++mt) {
        const int row = w * 32 + mt * 16 + l16;
#pragma unroll
        for (int dt = 0; dt < 4; ++dt)
            *(f16x4*)&Ab[(size_t)row * kD + dt * 16 + quad * 4] =
                pack4(o[mt][dt][0], o[mt][dt][1], o[mt][dt][2], o[mt][dt][3]);
        if (quad == 0) MLb[row] = make_float2(m_i[mt], l_i[mt]);
    }
}

// ---------------- combine (exp2 domain) ----------------
__global__ __launch_bounds__(256)
void fattn_combine(const _Float16* __restrict__ Ap,
                   const float2* __restrict__ MLp,
                   float* __restrict__ Og)
{
    const int idx = blockIdx.x * 256 + threadIdx.x;
    const int r = idx >> 4;
    const int c = (idx & 15) * 4;

    float m = -1e30f;
    float2 ml[KSPLIT];
#pragma unroll
    for (int s = 0; s < KSPLIT; ++s) {
        ml[s] = MLp[(size_t)s * kB * kSQ + r];
        m = fmaxf(m, ml[s].x);
    }
    float acc[4] = {0.f, 0.f, 0.f, 0.f};
    float lsum = 0.f;
#pragma unroll
    for (int s = 0; s < KSPLIT; ++s) {
        const float e = __builtin_amdgcn_exp2f(ml[s].x - m);
        lsum += e * ml[s].y;
        const f16x4 a = *(const f16x4*)&Ap[(size_t)s * APART + (size_t)r * kD + c];
#pragma unroll
        for (int j = 0; j < 4; ++j) acc[j] += e * (float)a[j];
    }
    const float inv = 1.0f / lsum;
    float4 res = make_float4(acc[0] * inv, acc[1] * inv, acc[2] * inv, acc[3] * inv);
    *(float4*)&Og[(size_t)r * kD + c] = res;
}

extern "C" void kernel_launch(void* const* d_in, const int* in_sizes, int n_in,
                              void* d_out, int out_size, void* d_ws, size_t ws_size,
                              hipStream_t stream) {
    const float* Q    = (const float*)d_in[0];
    const float* K    = (const float*)d_in[1];
    const float* V    = (const float*)d_in[2];
    const float* sdiv = (const float*)d_in[4];
    float* O = (float*)d_out;

    // workspace: Kh 4MB | Vt 4MB | Ap fp16 16.8MB | MLp 1MB
    _Float16* Kh  = (_Float16*)d_ws;
    _Float16* Vt  = Kh + (size_t)kB * kSK * kD;
    _Float16* Ap  = Vt + (size_t)kB * kSK * kD;
    float2*   MLp = (float2*)(Ap + (size_t)KSPLIT * APART);

    fattn_prepass<<<dim3(kSK / BK, kB), dim3(256), 0, stream>>>(K, V, Kh, Vt);
    fattn_partial<<<dim3((kSQ / BQ) * kB * KSPLIT), dim3(256), 0, stream>>>(Q, Kh, Vt, sdiv, Ap, MLp);
    fattn_combine<<<dim3(kB * kSQ * kD / (256 * 4)), dim3(256), 0, stream>>>(Ap, MLp, O);
}

// Round 12
// 137.964 us; speedup vs baseline: 1.0567x; 1.0567x over previous
//
#include <hip/hip_runtime.h>

// Flash attention forward, fp32 in/out, fp16 MFMA compute.
// B=8, SQ=SK=4096, D=64. scores = (Q/x5) K^T ; softmax ; O = P V.
// R12 = R11 + two work-reduction levers (R11 proved occupancy is costless:
// 24->32% occ gave 0 speedup; we're work/chain-bound on VALU+LDS):
//  - fused l-accumulation: ol = mfma(ones, pf, ol) computes row-sums inside
//    PV; deletes 16 adds + 2 ds_swizzle shuffles per mt-iter (+2 MFMA on the
//    19%-busy matrix pipe).
//  - MT=4 (BQ=256, grid 512, 2 blocks/CU): kf/vf LDS reads amortized over 4
//    M-tiles (-33% LDS work/output), staging DMA + FETCH halved per output.
// Rest: R7 global_load_lds dbuf staging, 1 barrier/iter, XCD-affine flat
// grid, exp2-domain softmax, shared 8 KB sP, KSPLIT=4, fp16 partials.

typedef _Float16 f16x8 __attribute__((ext_vector_type(8)));
typedef _Float16 f16x4 __attribute__((ext_vector_type(4)));
typedef __fp16   h16x2 __attribute__((ext_vector_type(2)));
typedef float    f32x4 __attribute__((ext_vector_type(4)));

constexpr int kB  = 8;
constexpr int kSQ = 4096;
constexpr int kSK = 4096;
constexpr int kD  = 64;
constexpr int KSPLIT = 4;
constexpr int SKH = kSK / KSPLIT;     // 1024 keys per split
constexpr int BQ  = 256;              // 4 waves x 64 Q rows (MT=4)
constexpr int MT  = 4;
constexpr int BK  = 64;
constexpr size_t APART = (size_t)kB * kSQ * kD;
constexpr float kLog2e = 1.44269504088896340736f;

static __device__ __forceinline__ f16x4 pack4(float a, float b, float c, float d) {
    h16x2 p0 = __builtin_amdgcn_cvt_pkrtz(a, b);
    h16x2 p1 = __builtin_amdgcn_cvt_pkrtz(c, d);
    f16x4 r;
    r[0] = (_Float16)p0[0]; r[1] = (_Float16)p0[1];
    r[2] = (_Float16)p1[0]; r[3] = (_Float16)p1[1];
    return r;
}
static __device__ __forceinline__ f16x8 pack8(const float4& a, const float4& c) {
    f16x4 lo = pack4(a.x, a.y, a.z, a.w);
    f16x4 hi = pack4(c.x, c.y, c.z, c.w);
    f16x8 f;
    f[0] = lo[0]; f[1] = lo[1]; f[2] = lo[2]; f[3] = lo[3];
    f[4] = hi[0]; f[5] = hi[1]; f[6] = hi[2]; f[7] = hi[3];
    return f;
}

typedef const __attribute__((address_space(1))) unsigned int* gu32p;
typedef __attribute__((address_space(3))) unsigned int* lu32p;
static __device__ __forceinline__ void gload_lds16(const void* g, void* l) {
    __builtin_amdgcn_global_load_lds((gu32p)g, (lu32p)l, 16, 0, 0);
}

// ---------------- pre-pass: K -> Kh (swizzled fp16), V -> Vt (transposed,
// tiled, swizzled fp16). Kh[b][k][blk fb^(k&7)][8]; Vt[b][kt][f][blk kb^(f&7)][8].
__global__ __launch_bounds__(256, 2)
void fattn_prepass(const float* __restrict__ Kg,
                   const float* __restrict__ Vg,
                   _Float16* __restrict__ Kh,
                   _Float16* __restrict__ Vt)
{
    __shared__ _Float16 tr[kD][BK];

    const int tid = threadIdx.x;
    const int kt  = blockIdx.x;
    const int b   = blockIdx.y;

    const int k = tid >> 2;
    const int p = tid & 3;
    const int gk = kt * BK + k;

    {
        const float* src = Kg + ((size_t)b * kSK + gk) * kD + p * 16;
        const float4 a0 = *(const float4*)(src + 0);
        const float4 a1 = *(const float4*)(src + 4);
        const float4 a2 = *(const float4*)(src + 8);
        const float4 a3 = *(const float4*)(src + 12);
        _Float16* dst = Kh + ((size_t)b * kSK + gk) * kD;
        const int fb0 = 2 * p, fb1 = 2 * p + 1;
        *(f16x8*)&dst[(fb0 ^ (gk & 7)) * 8] = pack8(a0, a1);
        *(f16x8*)&dst[(fb1 ^ (gk & 7)) * 8] = pack8(a2, a3);
    }
    {
        const float* src = Vg + ((size_t)b * kSK + gk) * kD + p * 16;
        const float4 a0 = *(const float4*)(src + 0);
        const float4 a1 = *(const float4*)(src + 4);
        const float4 a2 = *(const float4*)(src + 8);
        const float4 a3 = *(const float4*)(src + 12);
        const float v[16] = {a0.x,a0.y,a0.z,a0.w, a1.x,a1.y,a1.z,a1.w,
                             a2.x,a2.y,a2.z,a2.w, a3.x,a3.y,a3.z,a3.w};
#pragma unroll
        for (int j = 0; j < 16; ++j)
            tr[p * 16 + j][k] = (_Float16)v[j];
    }
    __syncthreads();
    {
        const int f  = tid >> 2;
        const int p2 = tid & 3;
        const f16x8 b0 = *(const f16x8*)&tr[f][p2 * 16 + 0];
        const f16x8 b1 = *(const f16x8*)&tr[f][p2 * 16 + 8];
        _Float16* dst = Vt + (((size_t)b * 64 + kt) * kD + f) * BK;
        const int kb0 = 2 * p2, kb1 = 2 * p2 + 1;
        *(f16x8*)&dst[(kb0 ^ (f & 7)) * 8] = b0;
        *(f16x8*)&dst[(kb1 ^ (f & 7)) * 8] = b1;
    }
}

// ---------------- main partial kernel ----------------
__global__ __launch_bounds__(256, 2)
void fattn_partial(const float* __restrict__ Qg,
                   const _Float16* __restrict__ Kh,
                   const _Float16* __restrict__ Vt,
                   const float* __restrict__ sdiv,
                   _Float16* __restrict__ Ap,   // [KSPLIT][B][SQ][D] unnormalized
                   float2* __restrict__ MLp)    // [KSPLIT][B][SQ] (m,l) exp2-domain
{
    __shared__ __align__(16) _Float16 sK[2][BK * kD];   // 16 KB
    __shared__ __align__(16) _Float16 sV[2][kD * BK];   // 16 KB
    __shared__ __align__(16) _Float16 sP[4][16][BK];    // 8 KB, shared across mt

    const int tid  = threadIdx.x;
    const int w    = tid >> 6;
    const int lane = tid & 63;
    const int l16  = lane & 15;
    const int quad = lane >> 4;
    const int sw   = (quad ^ (l16 & 7)) * 8;   // K/V fragment swizzle
    const int swp  = (l16 & 7) * 8;            // sP key-block swizzle

    // XCD-affine decode: flat = c + 32*q; c = (b,ks); all 16 q-blocks of one
    // K/V stream share an XCD (flat%8 invariant across q).
    const int flat = blockIdx.x;
    const int c    = flat & 31;
    const int qi   = flat >> 5;
    const int b    = c >> 2;      // KSPLIT = 4
    const int ks   = c & 3;
    const int qb   = qi * BQ;

    const float qscale = kLog2e / sdiv[0];   // exp2 domain

    const float* Qb = Qg + ((size_t)b * kSQ + qb) * kD;
    const _Float16* Khb = Kh + ((size_t)b * kSK + (size_t)ks * SKH) * kD;
    const _Float16* Vtb = Vt + (((size_t)b * 64 + (size_t)ks * (SKH / BK)) * kD) * BK;

    // ---- Q fragments: 4 M-tiles per wave (rows w*64 + mt*16 + l16) ----
    f16x8 qf[MT][2];
#pragma unroll
    for (int mt = 0; mt < MT; ++mt) {
        const float* qrow = Qb + (size_t)(w * 64 + mt * 16 + l16) * kD;
#pragma unroll
        for (int kk = 0; kk < 2; ++kk) {
            const float4 a = *(const float4*)(qrow + kk * 32 + quad * 8);
            const float4 cc = *(const float4*)(qrow + kk * 32 + quad * 8 + 4);
            float4 as = make_float4(a.x * qscale, a.y * qscale, a.z * qscale, a.w * qscale);
            float4 cs = make_float4(cc.x * qscale, cc.y * qscale, cc.z * qscale, cc.w * qscale);
            qf[mt][kk] = pack8(as, cs);
        }
    }

    // ones A-fragment for the fused-l MFMA
    f16x8 ones;
#pragma unroll
    for (int j = 0; j < 8; ++j) ones[j] = (_Float16)1.0f;

    // ---- async staging: 4 global_load_lds per wave ----
    auto stage = [&](int kt, int buf) {
        const char* gk = (const char*)(Khb + (size_t)kt * BK * kD) + w * 2048 + lane * 16;
        const char* gv = (const char*)(Vtb + (size_t)kt * kD * BK) + w * 2048 + lane * 16;
        char* lk = (char*)&sK[buf][0] + w * 2048;
        char* lv = (char*)&sV[buf][0] + w * 2048;
        gload_lds16(gk,        lk);
        gload_lds16(gk + 1024, lk + 1024);
        gload_lds16(gv,        lv);
        gload_lds16(gv + 1024, lv + 1024);
    };

    f32x4 o[MT][4];
    f32x4 ol[MT];                 // fused l accumulator (only [0] maintained)
    float m_i[MT];
#pragma unroll
    for (int mt = 0; mt < MT; ++mt) {
        m_i[mt] = -1e30f;
#pragma unroll
        for (int r = 0; r < 4; ++r) ol[mt][r] = 0.0f;
#pragma unroll
        for (int dt = 0; dt < 4; ++dt)
#pragma unroll
            for (int r = 0; r < 4; ++r) o[mt][dt][r] = 0.0f;
    }

    stage(0, 0);
    __syncthreads();

    const int nIter = SKH / BK;   // 16
    for (int kt = 0; kt < nIter; ++kt) {
        const int buf = kt & 1;
        const bool more = (kt + 1 < nIter);
        if (more) stage(kt + 1, buf ^ 1);   // DMA in flight during compute

        // ---- S^T = K Q^T (kf shared across 4 M-tiles) ----
        f32x4 s[MT][4];
#pragma unroll
        for (int nt = 0; nt < 4; ++nt) {
            const int krow = (nt * 16 + l16) * kD;
            const f16x8 kf0 = *(const f16x8*)&sK[buf][krow + sw];
            const f16x8 kf1 = *(const f16x8*)&sK[buf][krow + (sw ^ 32)];
#pragma unroll
            for (int mt = 0; mt < MT; ++mt) {
                f32x4 acc;
#pragma unroll
                for (int r = 0; r < 4; ++r) acc[r] = 0.0f;
                acc = __builtin_amdgcn_mfma_f32_16x16x32_f16(kf0, qf[mt][0], acc, 0, 0, 0);
                acc = __builtin_amdgcn_mfma_f32_16x16x32_f16(kf1, qf[mt][1], acc, 0, 0, 0);
                s[mt][nt] = acc;
            }
        }

        // ---- vf reads hoisted (shared across 4 M-tiles) ----
        f16x8 vf[4][2];
#pragma unroll
        for (int dt = 0; dt < 4; ++dt) {
            const int frow = (dt * 16 + l16) * BK;
            vf[dt][0] = *(const f16x8*)&sV[buf][frow + sw];
            vf[dt][1] = *(const f16x8*)&sV[buf][frow + (sw ^ 32)];
        }

        // ---- per-M-tile: softmax -> sP write -> pf read -> PV (+fused l).
        //      Shared sP buffer; DS ops in-order per wave keep it safe. ----
#pragma unroll
        for (int mt = 0; mt < MT; ++mt) {
            float ra = fmaxf(fmaxf(s[mt][0][0], s[mt][0][1]), fmaxf(s[mt][0][2], s[mt][0][3]));
            float rb = fmaxf(fmaxf(s[mt][1][0], s[mt][1][1]), fmaxf(s[mt][1][2], s[mt][1][3]));
            float rc = fmaxf(fmaxf(s[mt][2][0], s[mt][2][1]), fmaxf(s[mt][2][2], s[mt][2][3]));
            float rd = fmaxf(fmaxf(s[mt][3][0], s[mt][3][1]), fmaxf(s[mt][3][2], s[mt][3][3]));
            float rm = fmaxf(fmaxf(ra, rb), fmaxf(rc, rd));
            rm = fmaxf(rm, __shfl_xor(rm, 16, 64));
            rm = fmaxf(rm, __shfl_xor(rm, 32, 64));
            const float mnew = fmaxf(m_i[mt], rm);
#pragma unroll
            for (int nt = 0; nt < 4; ++nt)
#pragma unroll
                for (int r = 0; r < 4; ++r)
                    s[mt][nt][r] = __builtin_amdgcn_exp2f(s[mt][nt][r] - mnew);
            if (!__all(mnew == m_i[mt])) {      // max moved: rescale o and ol
                const float alpha = __builtin_amdgcn_exp2f(m_i[mt] - mnew);
                ol[mt][0] *= alpha;
#pragma unroll
                for (int dt = 0; dt < 4; ++dt)
#pragma unroll
                    for (int r = 0; r < 4; ++r) o[mt][dt][r] *= alpha;
            }
            m_i[mt] = mnew;

            // P -> sP (swizzled, unpadded; b64 writes <=2-way)
#pragma unroll
            for (int nt = 0; nt < 4; ++nt)
                *(f16x4*)&sP[w][l16][(nt * 16 + quad * 4) ^ swp] =
                    pack4(s[mt][nt][0], s[mt][nt][1], s[mt][nt][2], s[mt][nt][3]);

            // pf reads (b128 <=2-way) + PV + fused l (ones-MFMA row sum)
            const f16x8 pf0 = *(const f16x8*)&sP[w][l16][(quad * 8) ^ swp];
            const f16x8 pf1 = *(const f16x8*)&sP[w][l16][(32 + quad * 8) ^ swp];
#pragma unroll
            for (int dt = 0; dt < 4; ++dt) {
                o[mt][dt] = __builtin_amdgcn_mfma_f32_16x16x32_f16(vf[dt][0], pf0, o[mt][dt], 0, 0, 0);
                o[mt][dt] = __builtin_amdgcn_mfma_f32_16x16x32_f16(vf[dt][1], pf1, o[mt][dt], 0, 0, 0);
            }
            ol[mt] = __builtin_amdgcn_mfma_f32_16x16x32_f16(ones, pf0, ol[mt], 0, 0, 0);
            ol[mt] = __builtin_amdgcn_mfma_f32_16x16x32_f16(ones, pf1, ol[mt], 0, 0, 0);
        }

        __syncthreads();   // drains prefetch DMA (vmcnt) + LDS
    }

    // ---- epilogue ----
    _Float16* Ab = Ap + (size_t)ks * APART + ((size_t)b * kSQ + qb) * kD;
    float2* MLb = MLp + (size_t)ks * kB * kSQ + (size_t)b * kSQ + qb;
#pragma unroll
    for (int mt = 0; mt < MT; ++mt) {
        const int row = w * 64 + mt * 16 + l16;
#pragma unroll
        for (int dt = 0; dt < 4; ++dt)
            *(f16x4*)&Ab[(size_t)row * kD + dt * 16 + quad * 4] =
                pack4(o[mt][dt][0], o[mt][dt][1], o[mt][dt][2], o[mt][dt][3]);
        if (quad == 0) MLb[row] = make_float2(m_i[mt], ol[mt][0]);
    }
}

// ---------------- combine (exp2 domain) ----------------
__global__ __launch_bounds__(256)
void fattn_combine(const _Float16* __restrict__ Ap,
                   const float2* __restrict__ MLp,
                   float* __restrict__ Og)
{
    const int idx = blockIdx.x * 256 + threadIdx.x;
    const int r = idx >> 4;
    const int c = (idx & 15) * 4;

    float m = -1e30f;
    float2 ml[KSPLIT];
#pragma unroll
    for (int s = 0; s < KSPLIT; ++s) {
        ml[s] = MLp[(size_t)s * kB * kSQ + r];
        m = fmaxf(m, ml[s].x);
    }
    float acc[4] = {0.f, 0.f, 0.f, 0.f};
    float lsum = 0.f;
#pragma unroll
    for (int s = 0; s < KSPLIT; ++s) {
        const float e = __builtin_amdgcn_exp2f(ml[s].x - m);
        lsum += e * ml[s].y;
        const f16x4 a = *(const f16x4*)&Ap[(size_t)s * APART + (size_t)r * kD + c];
#pragma unroll
        for (int j = 0; j < 4; ++j) acc[j] += e * (float)a[j];
    }
    const float inv = 1.0f / lsum;
    float4 res = make_float4(acc[0] * inv, acc[1] * inv, acc[2] * inv, acc[3] * inv);
    *(float4*)&Og[(size_t)r * kD + c] = res;
}

extern "C" void kernel_launch(void* const* d_in, const int* in_sizes, int n_in,
                              void* d_out, int out_size, void* d_ws, size_t ws_size,
                              hipStream_t stream) {
    const float* Q    = (const float*)d_in[0];
    const float* K    = (const float*)d_in[1];
    const float* V    = (const float*)d_in[2];
    const float* sdiv = (const float*)d_in[4];
    float* O = (float*)d_out;

    // workspace: Kh 4MB | Vt 4MB | Ap fp16 16.8MB | MLp 1MB
    _Float16* Kh  = (_Float16*)d_ws;
    _Float16* Vt  = Kh + (size_t)kB * kSK * kD;
    _Float16* Ap  = Vt + (size_t)kB * kSK * kD;
    float2*   MLp = (float2*)(Ap + (size_t)KSPLIT * APART);

    fattn_prepass<<<dim3(kSK / BK, kB), dim3(256), 0, stream>>>(K, V, Kh, Vt);
    fattn_partial<<<dim3((kSQ / BQ) * kB * KSPLIT), dim3(256), 0, stream>>>(Q, Kh, Vt, sdiv, Ap, MLp);
    fattn_combine<<<dim3(kB * kSQ * kD / (256 * 4)), dim3(256), 0, stream>>>(Ap, MLp, O);
}